// Round 1
// baseline (295.039 us; speedup 1.0000x reference)
//
#include <hip/hip_runtime.h>
#include <hip/hip_bf16.h>

typedef unsigned short u16;
typedef __attribute__((ext_vector_type(8))) __bf16 bf16x8;
typedef __attribute__((ext_vector_type(4))) float f32x4;

#define SEQ 2048
#define NB 2
#define NH 16
#define HD 64
#define DM 1024
#define LDQKV 3072
#define KF 576   // folded feature K: 512 h1 + 63 feats + 1 pad

__device__ __forceinline__ u16 f2bf(float f) {
    unsigned u = __float_as_uint(f);
    unsigned r = u + 0x7FFFu + ((u >> 16) & 1u);
    return (u16)(r >> 16);
}
__device__ __forceinline__ float bf2f(u16 x) {
    return __uint_as_float(((unsigned)x) << 16);
}

// ---------------- weight transpose: dst[n*ldd + k] = bf16(src[k*N + n]) ----------------
__global__ __launch_bounds__(256) void transw_kernel(const float* __restrict__ src,
                                                     u16* __restrict__ dst, int N, int ldd) {
    __shared__ float tl[32][33];
    int tx = threadIdx.x, ty = threadIdx.y;
    int n = blockIdx.x * 32 + tx;
    int kbase = blockIdx.y * 32;
#pragma unroll
    for (int i = 0; i < 4; ++i)
        tl[ty + i * 8][tx] = src[(size_t)(kbase + ty + i * 8) * N + n];
    __syncthreads();
    int k = kbase + tx;
#pragma unroll
    for (int i = 0; i < 4; ++i) {
        int n2 = blockIdx.x * 32 + ty + i * 8;
        dst[(size_t)n2 * ldd + k] = f2bf(tl[tx][ty + i * 8]);
    }
}

// ---------------- fold small feature weights through fus_w into WcT rows 512..575 ------
__global__ __launch_bounds__(256) void fold_kernel(const float* __restrict__ log_w,
                                                   const float* __restrict__ prime_w,
                                                   const float* __restrict__ div_w,
                                                   const float* __restrict__ bit_w,
                                                   const float* __restrict__ fus_w,
                                                   u16* __restrict__ WcT) {
    const int r = blockIdx.y;  // 0..63
    const int n = blockIdx.x * 256 + threadIdx.x;
    if (r == 63) { WcT[(size_t)n * KF + 575] = 0; return; }
    const float* wrow; int chunk;
    if (r == 0)       { wrow = log_w;                 chunk = 0;   }
    else if (r < 11)  { wrow = prime_w + (r - 1) * 256; chunk = 256; }
    else if (r < 31)  { wrow = div_w + (r - 11) * 256;  chunk = 512; }
    else              { wrow = bit_w + (r - 31) * 256;  chunk = 768; }
    float acc = 0.f;
#pragma unroll 8
    for (int m = 0; m < 256; ++m)
        acc += wrow[m] * fus_w[(size_t)(chunk + m) * DM + n];
    WcT[(size_t)n * KF + 512 + r] = f2bf(acc);
}

// ---------------- constant bias vector for hidden ----------------
__global__ void cvec_kernel(const float* __restrict__ emb2_b, const float* __restrict__ fus_b,
                            const float* __restrict__ log_b, const float* __restrict__ prime_b,
                            const float* __restrict__ div_b, const float* __restrict__ bit_b,
                            const float* __restrict__ fus_w, float* __restrict__ cvec) {
    int n = blockIdx.x * 256 + threadIdx.x;
    float acc = emb2_b[n] + fus_b[n];
#pragma unroll 4
    for (int m = 0; m < 256; ++m) {
        acc += log_b[m]   * fus_w[(size_t)m * DM + n];
        acc += prime_b[m] * fus_w[(size_t)(256 + m) * DM + n];
        acc += div_b[m]   * fus_w[(size_t)(512 + m) * DM + n];
        acc += bit_b[m]   * fus_w[(size_t)(768 + m) * DM + n];
    }
    cvec[n] = acc;
}

__global__ void qkvb_kernel(const float* __restrict__ q_b, const float* __restrict__ k_b,
                            const float* __restrict__ v_b, float* __restrict__ qkvb) {
    int i = blockIdx.x * 256 + threadIdx.x;  // 0..3071
    qkvb[i] = (i < 1024) ? q_b[i] : (i < 2048 ? k_b[i - 1024] : v_b[i - 2048]);
}

// ---------------- per-token feature vector F (4096 x 576 bf16) ----------------
__global__ __launch_bounds__(256) void feat_kernel(const int* __restrict__ enc,
                                                   const float* __restrict__ emb1_w,
                                                   const float* __restrict__ emb1_b,
                                                   u16* __restrict__ F) {
    const int tok = blockIdx.x;
    const int t = threadIdx.x;
    int e = enc[tok];
    float ef = (float)e;
    float nrm = ef / 2147483647.0f;
    for (int k = t; k < 512; k += 256)
        F[(size_t)tok * KF + k] = f2bf(fmaxf(nrm * emb1_w[k] + emb1_b[k], 0.f));
    if (t < 64) {
        float v;
        if (t == 0) v = logf(ef + 1.f);
        else if (t < 11) {
            const int pr[10] = {2, 3, 5, 7, 11, 13, 17, 19, 23, 29};
            v = (e % pr[t - 1] == 0) ? 1.f : 0.f;
        } else if (t < 31) {
            int tv = t - 11 + 2;
            v = (float)(e % tv) / (float)tv;
        } else if (t < 63) {
            int sh = t - 31;
            v = (float)((e >> sh) & 1);
        } else v = 0.f;
        F[(size_t)tok * KF + 512 + t] = f2bf(v);
    }
}

// ---------------- GEMM: C[MxN] = A(bf16 MxK) @ BT(bf16 NxK)^T + bias ----------------
template <int OUT_BF16>
__global__ __launch_bounds__(256) void gemm_kernel(const u16* __restrict__ A,
                                                   const u16* __restrict__ BT,
                                                   const float* __restrict__ bias,
                                                   void* __restrict__ Cv,
                                                   int M, int N, int K) {
    __shared__ u16 As[128][40];
    __shared__ u16 Bs[128][40];
    const int t = threadIdx.x;
    const int m0 = blockIdx.y * 128, n0 = blockIdx.x * 128;
    const int w = t >> 6, l = t & 63, lr = l & 15, lg = l >> 4;
    const int wm = (w >> 1) * 64, wn = (w & 1) * 64;
    f32x4 acc[4][4] = {};
    const int ar = t >> 1, ac = (t & 1) * 16;
    for (int k0 = 0; k0 < K; k0 += 32) {
        __syncthreads();
        {
            const int4* ga = (const int4*)&A[(size_t)(m0 + ar) * K + k0 + ac];
            int4 v0 = ga[0], v1 = ga[1];
            *(int4*)&As[ar][ac] = v0;
            *(int4*)&As[ar][ac + 8] = v1;
            const int4* gb = (const int4*)&BT[(size_t)(n0 + ar) * K + k0 + ac];
            int4 u0 = gb[0], u1 = gb[1];
            *(int4*)&Bs[ar][ac] = u0;
            *(int4*)&Bs[ar][ac + 8] = u1;
        }
        __syncthreads();
        bf16x8 a[4], b[4];
#pragma unroll
        for (int i = 0; i < 4; ++i) a[i] = *(const bf16x8*)&As[wm + i * 16 + lr][lg * 8];
#pragma unroll
        for (int i = 0; i < 4; ++i) b[i] = *(const bf16x8*)&Bs[wn + i * 16 + lr][lg * 8];
#pragma unroll
        for (int mi = 0; mi < 4; ++mi)
#pragma unroll
            for (int ni = 0; ni < 4; ++ni)
                acc[mi][ni] = __builtin_amdgcn_mfma_f32_16x16x32_bf16(a[mi], b[ni], acc[mi][ni], 0, 0, 0);
    }
#pragma unroll
    for (int mi = 0; mi < 4; ++mi)
#pragma unroll
        for (int ni = 0; ni < 4; ++ni)
#pragma unroll
            for (int r = 0; r < 4; ++r) {
                int row = m0 + wm + mi * 16 + lg * 4 + r;
                int col = n0 + wn + ni * 16 + lr;
                float v = acc[mi][ni][r] + bias[col];
                if (OUT_BF16)
                    ((u16*)Cv)[(size_t)row * N + col] = f2bf(v);
                else
                    ((float*)Cv)[(size_t)row * N + col] = v;
            }
}

// ---------------- V transpose: vT[b][h][d][s] = v[b][s][h][d] ----------------
__global__ __launch_bounds__(256) void vtrans_kernel(const u16* __restrict__ qkv,
                                                     u16* __restrict__ vT) {
    __shared__ u16 tile[64][72];
    int t = threadIdx.x;
    int s0 = blockIdx.x * 64, h = blockIdx.y, b = blockIdx.z;
    int sr = t >> 2, sc = (t & 3) * 16;
    const int4* g = (const int4*)&qkv[(size_t)(b * SEQ + s0 + sr) * LDQKV + 2048 + h * HD + sc];
    int4 v0 = g[0], v1 = g[1];
    *(int4*)&tile[sr][sc] = v0;
    *(int4*)&tile[sr][sc + 8] = v1;
    __syncthreads();
    int dl = sr, j0 = sc;
    u16 tmp[16];
#pragma unroll
    for (int jj = 0; jj < 16; ++jj) tmp[jj] = tile[j0 + jj][dl];
    u16* out = &vT[(size_t)((b * NH + h) * HD + dl) * SEQ + s0 + j0];
    *(int4*)&out[0] = *(int4*)&tmp[0];
    *(int4*)&out[8] = *(int4*)&tmp[8];
}

// ---------------- gcd-ish bias matrix (B,S,S) bf16 ----------------
__global__ __launch_bounds__(256) void biasm_kernel(const int* __restrict__ enc,
                                                    u16* __restrict__ biasM) {
    int j = blockIdx.x * 256 + threadIdx.x;
    int i = blockIdx.y;
    int b = blockIdx.z;
    unsigned ei = (unsigned)enc[b * SEQ + i];
    unsigned ej = (unsigned)enc[b * SEQ + j];
    unsigned r1 = ei % (ej + 1u);
    unsigned r2 = ej % (ei + 1u);
    unsigned g = min(r1, r2);
    unsigned mx = max(ei, ej) + 1u;
    float v = (i == j) ? 0.f : (float)g / (float)mx;
    biasM[((size_t)b * SEQ + i) * SEQ + j] = f2bf(v);
}

// ---------------- fused attention: flash-style with additive bias ----------------
__global__ __launch_bounds__(256) void attn_kernel(const u16* __restrict__ qkv,
                                                   const u16* __restrict__ vT,
                                                   const u16* __restrict__ biasM,
                                                   const float* __restrict__ arith_bias,
                                                   const float* __restrict__ gcd_w,
                                                   u16* __restrict__ attn_out) {
    __shared__ u16 Kt[64][72];
    __shared__ u16 Vt[64][72];
    __shared__ u16 Pl[4][16][72];
    const int t = threadIdx.x, w = t >> 6, l = t & 63, lr = l & 15, lg = l >> 4;
    const int qt = blockIdx.x, h = blockIdx.y, b = blockIdx.z;
    const float gcdw = gcd_w[0], ab = arith_bias[h];

    bf16x8 qf[2];
    const int qrow = qt * 64 + w * 16 + lr;
#pragma unroll
    for (int kk = 0; kk < 2; ++kk)
        qf[kk] = *(const bf16x8*)&qkv[(size_t)(b * SEQ + qrow) * LDQKV + h * HD + kk * 32 + lg * 8];

    float m_s[4], l_s[4];
    f32x4 acc_o[4] = {};
#pragma unroll
    for (int r = 0; r < 4; ++r) { m_s[r] = -1e30f; l_s[r] = 0.f; }
    const int sr = t >> 2, sc = (t & 3) * 16;

    for (int jt = 0; jt < 32; ++jt) {
        const int jb = jt * 64;
        __syncthreads();
        {
            const int4* gk = (const int4*)&qkv[(size_t)(b * SEQ + jb + sr) * LDQKV + 1024 + h * HD + sc];
            int4 v0 = gk[0], v1 = gk[1];
            *(int4*)&Kt[sr][sc] = v0;
            *(int4*)&Kt[sr][sc + 8] = v1;
            const int4* gv = (const int4*)&vT[(size_t)((b * NH + h) * HD + sr) * SEQ + jb + sc];
            int4 u0 = gv[0], u1 = gv[1];
            *(int4*)&Vt[sr][sc] = u0;
            *(int4*)&Vt[sr][sc + 8] = u1;
        }
        __syncthreads();
        f32x4 accs[4] = {};
#pragma unroll
        for (int kk = 0; kk < 2; ++kk)
#pragma unroll
            for (int ni = 0; ni < 4; ++ni) {
                bf16x8 bk = *(const bf16x8*)&Kt[ni * 16 + lr][kk * 32 + lg * 8];
                accs[ni] = __builtin_amdgcn_mfma_f32_16x16x32_bf16(qf[kk], bk, accs[ni], 0, 0, 0);
            }
        // scores = qk/8 + bias*gcdw + ab
        float sv[4][4];
        const int i_g = qt * 64 + w * 16 + lg * 4;
#pragma unroll
        for (int ni = 0; ni < 4; ++ni) {
            int j_g = jb + ni * 16 + lr;
#pragma unroll
            for (int r = 0; r < 4; ++r) {
                float bias_v = bf2f(biasM[((size_t)b * SEQ + i_g + r) * SEQ + j_g]);
                sv[ni][r] = accs[ni][r] * 0.125f + bias_v * gcdw + ab;
            }
        }
        // online softmax per row
        float p[4][4];
#pragma unroll
        for (int r = 0; r < 4; ++r) {
            float mx = fmaxf(fmaxf(sv[0][r], sv[1][r]), fmaxf(sv[2][r], sv[3][r]));
            mx = fmaxf(mx, __shfl_xor(mx, 1));
            mx = fmaxf(mx, __shfl_xor(mx, 2));
            mx = fmaxf(mx, __shfl_xor(mx, 4));
            mx = fmaxf(mx, __shfl_xor(mx, 8));
            float mn = fmaxf(m_s[r], mx);
            float alpha = __expf(m_s[r] - mn);
            float ps = 0.f;
#pragma unroll
            for (int ni = 0; ni < 4; ++ni) {
                float e = __expf(sv[ni][r] - mn);
                p[ni][r] = e;
                ps += e;
            }
            ps += __shfl_xor(ps, 1);
            ps += __shfl_xor(ps, 2);
            ps += __shfl_xor(ps, 4);
            ps += __shfl_xor(ps, 8);
            l_s[r] = l_s[r] * alpha + ps;
            m_s[r] = mn;
#pragma unroll
            for (int ni = 0; ni < 4; ++ni) acc_o[ni][r] *= alpha;
        }
        // P -> per-wave LDS, reread as A-fragments
#pragma unroll
        for (int ni = 0; ni < 4; ++ni)
#pragma unroll
            for (int r = 0; r < 4; ++r)
                Pl[w][lg * 4 + r][ni * 16 + lr] = f2bf(p[ni][r]);
        asm volatile("s_waitcnt lgkmcnt(0)" ::: "memory");
        bf16x8 pa[2];
#pragma unroll
        for (int kk = 0; kk < 2; ++kk)
            pa[kk] = *(const bf16x8*)&Pl[w][lr][kk * 32 + lg * 8];
#pragma unroll
        for (int kk = 0; kk < 2; ++kk)
#pragma unroll
            for (int nd = 0; nd < 4; ++nd) {
                bf16x8 bv = *(const bf16x8*)&Vt[nd * 16 + lr][kk * 32 + lg * 8];
                acc_o[nd] = __builtin_amdgcn_mfma_f32_16x16x32_bf16(pa[kk], bv, acc_o[nd], 0, 0, 0);
            }
    }
#pragma unroll
    for (int r = 0; r < 4; ++r) {
        float inv = 1.f / l_s[r];
        int i_g = qt * 64 + w * 16 + lg * 4 + r;
#pragma unroll
        for (int nd = 0; nd < 4; ++nd) {
            int d = nd * 16 + lr;
            attn_out[(size_t)(b * SEQ + i_g) * DM + h * HD + d] = f2bf(acc_o[nd][r] * inv);
        }
    }
}

extern "C" void kernel_launch(void* const* d_in, const int* in_sizes, int n_in,
                              void* d_out, int out_size, void* d_ws, size_t ws_size,
                              hipStream_t stream) {
    const float* q_w    = (const float*)d_in[0];
    const float* q_b    = (const float*)d_in[1];
    const float* k_w    = (const float*)d_in[2];
    const float* k_b    = (const float*)d_in[3];
    const float* v_w    = (const float*)d_in[4];
    const float* v_b    = (const float*)d_in[5];
    const float* o_w    = (const float*)d_in[6];
    const float* o_b    = (const float*)d_in[7];
    const float* emb1_w = (const float*)d_in[8];
    const float* emb1_b = (const float*)d_in[9];
    const float* emb2_w = (const float*)d_in[10];
    const float* emb2_b = (const float*)d_in[11];
    const float* log_w  = (const float*)d_in[12];
    const float* log_b  = (const float*)d_in[13];
    const float* prime_w= (const float*)d_in[14];
    const float* prime_b= (const float*)d_in[15];
    const float* div_w  = (const float*)d_in[16];
    const float* div_b  = (const float*)d_in[17];
    const float* bit_w  = (const float*)d_in[18];
    const float* bit_b  = (const float*)d_in[19];
    const float* fus_w  = (const float*)d_in[20];
    const float* fus_b  = (const float*)d_in[21];
    const float* arith_bias = (const float*)d_in[22];
    const float* gcd_weight = (const float*)d_in[23];
    const int*   enc    = (const int*)d_in[24];

    char* ws = (char*)d_ws;
    size_t off = 0;
    auto alloc = [&](size_t bytes) {
        char* p = ws + off;
        off += (bytes + 255) & ~size_t(255);
        return p;
    };
    u16*   WcT    = (u16*)alloc((size_t)DM * KF * 2);
    u16*   WqkvT  = (u16*)alloc((size_t)3072 * DM * 2);
    u16*   WoT    = (u16*)alloc((size_t)DM * DM * 2);
    float* cvec   = (float*)alloc(DM * 4);
    float* qkvb   = (float*)alloc(3072 * 4);
    u16*   F      = (u16*)alloc((size_t)NB * SEQ * KF * 2);
    u16*   hidden = (u16*)alloc((size_t)NB * SEQ * DM * 2);
    u16*   qkv    = (u16*)alloc((size_t)NB * SEQ * LDQKV * 2);
    u16*   vT     = (u16*)alloc((size_t)NB * NH * HD * SEQ * 2);
    u16*   biasM  = (u16*)alloc((size_t)NB * SEQ * SEQ * 2);
    u16*   attn_o = (u16*)alloc((size_t)NB * SEQ * DM * 2);
    (void)ws_size; (void)n_in; (void)in_sizes; (void)out_size;

    // weight prep
    transw_kernel<<<dim3(32, 16), dim3(32, 8), 0, stream>>>(emb2_w, WcT, DM, KF);
    transw_kernel<<<dim3(32, 32), dim3(32, 8), 0, stream>>>(q_w, WqkvT, DM, DM);
    transw_kernel<<<dim3(32, 32), dim3(32, 8), 0, stream>>>(k_w, WqkvT + (size_t)1024 * DM, DM, DM);
    transw_kernel<<<dim3(32, 32), dim3(32, 8), 0, stream>>>(v_w, WqkvT + (size_t)2048 * DM, DM, DM);
    transw_kernel<<<dim3(32, 32), dim3(32, 8), 0, stream>>>(o_w, WoT, DM, DM);
    fold_kernel<<<dim3(4, 64), 256, 0, stream>>>(log_w, prime_w, div_w, bit_w, fus_w, WcT);
    cvec_kernel<<<4, 256, 0, stream>>>(emb2_b, fus_b, log_b, prime_b, div_b, bit_b, fus_w, cvec);
    qkvb_kernel<<<12, 256, 0, stream>>>(q_b, k_b, v_b, qkvb);

    // features + hidden
    feat_kernel<<<NB * SEQ, 256, 0, stream>>>(enc, emb1_w, emb1_b, F);
    gemm_kernel<1><<<dim3(DM / 128, NB * SEQ / 128), 256, 0, stream>>>(F, WcT, cvec, hidden,
                                                                       NB * SEQ, DM, KF);
    // qkv
    gemm_kernel<1><<<dim3(3072 / 128, NB * SEQ / 128), 256, 0, stream>>>(hidden, WqkvT, qkvb, qkv,
                                                                         NB * SEQ, 3072, DM);
    vtrans_kernel<<<dim3(SEQ / 64, NH, NB), 256, 0, stream>>>(qkv, vT);
    biasm_kernel<<<dim3(SEQ / 256, SEQ, NB), 256, 0, stream>>>(enc, biasM);
    attn_kernel<<<dim3(SEQ / 64, NH, NB), 256, 0, stream>>>(qkv, vT, biasM, arith_bias, gcd_weight, attn_o);
    // output projection (fp32 out)
    gemm_kernel<0><<<dim3(DM / 128, NB * SEQ / 128), 256, 0, stream>>>(attn_o, WoT, o_b, d_out,
                                                                       NB * SEQ, DM, DM);
}

// Round 2
// 292.702 us; speedup vs baseline: 1.0080x; 1.0080x over previous
//
#include <hip/hip_runtime.h>
#include <hip/hip_bf16.h>

typedef unsigned short u16;
typedef __attribute__((ext_vector_type(8))) __bf16 bf16x8;
typedef __attribute__((ext_vector_type(4))) float f32x4;

#define SEQ 2048
#define NB 2
#define NH 16
#define HD 64
#define DM 1024
#define LDQKV 3072
#define KF 576   // folded feature K: 512 h1 + 63 feats + 1 pad
#define LOG2E 1.4426950408889634f

__device__ __forceinline__ u16 f2bf(float f) {
    unsigned u = __float_as_uint(f);
    unsigned r = u + 0x7FFFu + ((u >> 16) & 1u);
    return (u16)(r >> 16);
}
__device__ __forceinline__ float bf2f(u16 x) {
    return __uint_as_float(((unsigned)x) << 16);
}

// ---------------- weight transpose: dst[n*ldd + k] = bf16(src[k*N + n]) ----------------
__global__ __launch_bounds__(256) void transw_kernel(const float* __restrict__ src,
                                                     u16* __restrict__ dst, int N, int ldd) {
    __shared__ float tl[32][33];
    int tx = threadIdx.x, ty = threadIdx.y;
    int n = blockIdx.x * 32 + tx;
    int kbase = blockIdx.y * 32;
#pragma unroll
    for (int i = 0; i < 4; ++i)
        tl[ty + i * 8][tx] = src[(size_t)(kbase + ty + i * 8) * N + n];
    __syncthreads();
    int k = kbase + tx;
#pragma unroll
    for (int i = 0; i < 4; ++i) {
        int n2 = blockIdx.x * 32 + ty + i * 8;
        dst[(size_t)n2 * ldd + k] = f2bf(tl[tx][ty + i * 8]);
    }
}

// ---------------- fold small feature weights through fus_w into WcT rows 512..575 ------
__global__ __launch_bounds__(256) void fold_kernel(const float* __restrict__ log_w,
                                                   const float* __restrict__ prime_w,
                                                   const float* __restrict__ div_w,
                                                   const float* __restrict__ bit_w,
                                                   const float* __restrict__ fus_w,
                                                   u16* __restrict__ WcT) {
    const int r = blockIdx.y;  // 0..63
    const int n = blockIdx.x * 256 + threadIdx.x;
    if (r == 63) { WcT[(size_t)n * KF + 575] = 0; return; }
    const float* wrow; int chunk;
    if (r == 0)       { wrow = log_w;                 chunk = 0;   }
    else if (r < 11)  { wrow = prime_w + (r - 1) * 256; chunk = 256; }
    else if (r < 31)  { wrow = div_w + (r - 11) * 256;  chunk = 512; }
    else              { wrow = bit_w + (r - 31) * 256;  chunk = 768; }
    float acc = 0.f;
#pragma unroll 8
    for (int m = 0; m < 256; ++m)
        acc += wrow[m] * fus_w[(size_t)(chunk + m) * DM + n];
    WcT[(size_t)n * KF + 512 + r] = f2bf(acc);
}

// ---------------- constant bias vector for hidden ----------------
__global__ void cvec_kernel(const float* __restrict__ emb2_b, const float* __restrict__ fus_b,
                            const float* __restrict__ log_b, const float* __restrict__ prime_b,
                            const float* __restrict__ div_b, const float* __restrict__ bit_b,
                            const float* __restrict__ fus_w, float* __restrict__ cvec) {
    int n = blockIdx.x * 256 + threadIdx.x;
    float acc = emb2_b[n] + fus_b[n];
#pragma unroll 4
    for (int m = 0; m < 256; ++m) {
        acc += log_b[m]   * fus_w[(size_t)m * DM + n];
        acc += prime_b[m] * fus_w[(size_t)(256 + m) * DM + n];
        acc += div_b[m]   * fus_w[(size_t)(512 + m) * DM + n];
        acc += bit_b[m]   * fus_w[(size_t)(768 + m) * DM + n];
    }
    cvec[n] = acc;
}

__global__ void qkvb_kernel(const float* __restrict__ q_b, const float* __restrict__ k_b,
                            const float* __restrict__ v_b, float* __restrict__ qkvb) {
    int i = blockIdx.x * 256 + threadIdx.x;  // 0..3071
    qkvb[i] = (i < 1024) ? q_b[i] : (i < 2048 ? k_b[i - 1024] : v_b[i - 2048]);
}

// ---------------- per-token feature vector F (4096 x 576 bf16) ----------------
__global__ __launch_bounds__(256) void feat_kernel(const int* __restrict__ enc,
                                                   const float* __restrict__ emb1_w,
                                                   const float* __restrict__ emb1_b,
                                                   u16* __restrict__ F) {
    const int tok = blockIdx.x;
    const int t = threadIdx.x;
    int e = enc[tok];
    float ef = (float)e;
    float nrm = ef / 2147483647.0f;
    for (int k = t; k < 512; k += 256)
        F[(size_t)tok * KF + k] = f2bf(fmaxf(nrm * emb1_w[k] + emb1_b[k], 0.f));
    if (t < 64) {
        float v;
        if (t == 0) v = logf(ef + 1.f);
        else if (t < 11) {
            const int pr[10] = {2, 3, 5, 7, 11, 13, 17, 19, 23, 29};
            v = (e % pr[t - 1] == 0) ? 1.f : 0.f;
        } else if (t < 31) {
            int tv = t - 11 + 2;
            v = (float)(e % tv) / (float)tv;
        } else if (t < 63) {
            int sh = t - 31;
            v = (float)((e >> sh) & 1);
        } else v = 0.f;
        F[(size_t)tok * KF + 512 + t] = f2bf(v);
    }
}

// ---------------- GEMM: C[MxN] = A(bf16 MxK) @ BT(bf16 NxK)^T + bias ----------------
template <int OUT_BF16>
__global__ __launch_bounds__(256) void gemm_kernel(const u16* __restrict__ A,
                                                   const u16* __restrict__ BT,
                                                   const float* __restrict__ bias,
                                                   void* __restrict__ Cv,
                                                   int M, int N, int K) {
    __shared__ u16 As[128][40];
    __shared__ u16 Bs[128][40];
    const int t = threadIdx.x;
    const int m0 = blockIdx.y * 128, n0 = blockIdx.x * 128;
    const int w = t >> 6, l = t & 63, lr = l & 15, lg = l >> 4;
    const int wm = (w >> 1) * 64, wn = (w & 1) * 64;
    f32x4 acc[4][4] = {};
    const int ar = t >> 1, ac = (t & 1) * 16;
    for (int k0 = 0; k0 < K; k0 += 32) {
        __syncthreads();
        {
            const int4* ga = (const int4*)&A[(size_t)(m0 + ar) * K + k0 + ac];
            int4 v0 = ga[0], v1 = ga[1];
            *(int4*)&As[ar][ac] = v0;
            *(int4*)&As[ar][ac + 8] = v1;
            const int4* gb = (const int4*)&BT[(size_t)(n0 + ar) * K + k0 + ac];
            int4 u0 = gb[0], u1 = gb[1];
            *(int4*)&Bs[ar][ac] = u0;
            *(int4*)&Bs[ar][ac + 8] = u1;
        }
        __syncthreads();
        bf16x8 a[4], b[4];
#pragma unroll
        for (int i = 0; i < 4; ++i) a[i] = *(const bf16x8*)&As[wm + i * 16 + lr][lg * 8];
#pragma unroll
        for (int i = 0; i < 4; ++i) b[i] = *(const bf16x8*)&Bs[wn + i * 16 + lr][lg * 8];
#pragma unroll
        for (int mi = 0; mi < 4; ++mi)
#pragma unroll
            for (int ni = 0; ni < 4; ++ni)
                acc[mi][ni] = __builtin_amdgcn_mfma_f32_16x16x32_bf16(a[mi], b[ni], acc[mi][ni], 0, 0, 0);
    }
#pragma unroll
    for (int mi = 0; mi < 4; ++mi)
#pragma unroll
        for (int ni = 0; ni < 4; ++ni)
#pragma unroll
            for (int r = 0; r < 4; ++r) {
                int row = m0 + wm + mi * 16 + lg * 4 + r;
                int col = n0 + wn + ni * 16 + lr;
                float v = acc[mi][ni][r] + bias[col];
                if (OUT_BF16)
                    ((u16*)Cv)[(size_t)row * N + col] = f2bf(v);
                else
                    ((float*)Cv)[(size_t)row * N + col] = v;
            }
}

// ---------------- V transpose: vT[b][h][d][s] = v[b][s][h][d] ----------------
__global__ __launch_bounds__(256) void vtrans_kernel(const u16* __restrict__ qkv,
                                                     u16* __restrict__ vT) {
    __shared__ u16 tile[64][72];
    int t = threadIdx.x;
    int s0 = blockIdx.x * 64, h = blockIdx.y, b = blockIdx.z;
    int sr = t >> 2, sc = (t & 3) * 16;
    const int4* g = (const int4*)&qkv[(size_t)(b * SEQ + s0 + sr) * LDQKV + 2048 + h * HD + sc];
    int4 v0 = g[0], v1 = g[1];
    *(int4*)&tile[sr][sc] = v0;
    *(int4*)&tile[sr][sc + 8] = v1;
    __syncthreads();
    int dl = sr, j0 = sc;
    u16 tmp[16];
#pragma unroll
    for (int jj = 0; jj < 16; ++jj) tmp[jj] = tile[j0 + jj][dl];
    u16* out = &vT[(size_t)((b * NH + h) * HD + dl) * SEQ + s0 + j0];
    *(int4*)&out[0] = *(int4*)&tmp[0];
    *(int4*)&out[8] = *(int4*)&tmp[8];
}

// ---------------- gcd-ish bias matrix (B,S,S) bf16, pre-scaled by gcd_w*log2(e) --------
__global__ __launch_bounds__(256) void biasm_kernel(const int* __restrict__ enc,
                                                    const float* __restrict__ gcd_w,
                                                    u16* __restrict__ biasM) {
    int j = blockIdx.x * 256 + threadIdx.x;
    int i = blockIdx.y;
    int b = blockIdx.z;
    unsigned ei = (unsigned)enc[b * SEQ + i];
    unsigned ej = (unsigned)enc[b * SEQ + j];
    unsigned r1 = ei % (ej + 1u);
    unsigned r2 = ej % (ei + 1u);
    unsigned g = min(r1, r2);
    unsigned mx = max(ei, ej) + 1u;
    float v = (i == j) ? 0.f : (float)g / (float)mx;
    biasM[((size_t)b * SEQ + i) * SEQ + j] = f2bf(v * (gcd_w[0] * LOG2E));
}

// ---------------- fused attention: flash-style, KVBLK=128, LDS bias, log2 domain -------
#define KVB 128
__global__ __launch_bounds__(256) void attn_kernel(const u16* __restrict__ qkv,
                                                   const u16* __restrict__ vT,
                                                   const u16* __restrict__ biasM,
                                                   u16* __restrict__ attn_out) {
    __shared__ u16 Kt[KVB][72];    // K rows j, cols d
    __shared__ u16 Vt[HD][KVB + 8];  // V^T rows d, cols j
    __shared__ u16 BP[64][KVB + 8];  // bias tile, overwritten per-wave by P
    const int t = threadIdx.x, w = t >> 6, l = t & 63, lr = l & 15, lg = l >> 4;
    const int qt = blockIdx.x, h = blockIdx.y, b = blockIdx.z;
    const int i0 = qt * 64;
    const float C1 = 0.125f * LOG2E;   // qk scale folded with log2(e)

    // Q fragments (A-operand): row = lr within wave's 16 rows
    bf16x8 qf[2];
    const int qrow = i0 + w * 16 + lr;
#pragma unroll
    for (int kk = 0; kk < 2; ++kk)
        qf[kk] = *(const bf16x8*)&qkv[(size_t)(b * SEQ + qrow) * LDQKV + h * HD + kk * 32 + lg * 8];

    // per-thread staging addresses (chunk id c = t + 256*i)
    const int rK = t >> 3, cK = (t & 7) * 8;       // K: 128 rows x 8 chunks
    const int rV = t >> 4, cV = (t & 15) * 8;      // V/B: 64(16*4) rows x 16 chunks
    const u16* gK = &qkv[(size_t)(b * SEQ + rK) * LDQKV + 1024 + h * HD + cK];
    const u16* gV = &vT[(size_t)((b * NH + h) * HD + rV) * SEQ + cV];
    const u16* gB = &biasM[((size_t)b * SEQ + i0 + rV) * SEQ + cV];

    float m_s[4], l_s[4];
    f32x4 acc_o[4] = {};
#pragma unroll
    for (int r = 0; r < 4; ++r) { m_s[r] = -1e30f; l_s[r] = 0.f; }

    for (int jt = 0; jt < SEQ / KVB; ++jt) {
        const int jb = jt * KVB;
        __syncthreads();
        // ---- cooperative stage: K(16KB) + V^T(16KB) + bias(16KB) ----
        {
            int4 kv[4], vv[4], bv[4];
#pragma unroll
            for (int i = 0; i < 4; ++i) kv[i] = *(const int4*)&gK[(size_t)(jb + 32 * i) * LDQKV];
#pragma unroll
            for (int i = 0; i < 4; ++i) vv[i] = *(const int4*)&gV[(size_t)(16 * i) * SEQ + jb];
#pragma unroll
            for (int i = 0; i < 4; ++i) bv[i] = *(const int4*)&gB[(size_t)(16 * i) * SEQ + jb];
#pragma unroll
            for (int i = 0; i < 4; ++i) *(int4*)&Kt[rK + 32 * i][cK] = kv[i];
#pragma unroll
            for (int i = 0; i < 4; ++i) *(int4*)&Vt[rV + 16 * i][cV] = vv[i];
#pragma unroll
            for (int i = 0; i < 4; ++i) *(int4*)&BP[rV + 16 * i][cV] = bv[i];
        }
        __syncthreads();

        // ---- QK^T: 16 MFMAs -> s[ni][r] = scores for row (w*16+lg*4+r), col jb+ni*16+lr
        f32x4 s[8] = {};
#pragma unroll
        for (int kk = 0; kk < 2; ++kk)
#pragma unroll
            for (int ni = 0; ni < 8; ++ni) {
                bf16x8 bk = *(const bf16x8*)&Kt[ni * 16 + lr][kk * 32 + lg * 8];
                s[ni] = __builtin_amdgcn_mfma_f32_16x16x32_bf16(qf[kk], bk, s[ni], 0, 0, 0);
            }

        // ---- add bias (already *gcdw*log2e), scale qk by 0.125*log2e ----
        const int pr = w * 16 + lg * 4;  // wave's row base in BP
#pragma unroll
        for (int ni = 0; ni < 8; ++ni)
#pragma unroll
            for (int r = 0; r < 4; ++r) {
                float bvv = bf2f(BP[pr + r][ni * 16 + lr]);
                s[ni][r] = s[ni][r] * C1 + bvv;
            }

        // ---- row max (this tile) ----
        float tm[4];
#pragma unroll
        for (int r = 0; r < 4; ++r) {
            float mx = s[0][r];
#pragma unroll
            for (int ni = 1; ni < 8; ++ni) mx = fmaxf(mx, s[ni][r]);
            mx = fmaxf(mx, __shfl_xor(mx, 1));
            mx = fmaxf(mx, __shfl_xor(mx, 2));
            mx = fmaxf(mx, __shfl_xor(mx, 4));
            mx = fmaxf(mx, __shfl_xor(mx, 8));
            tm[r] = mx;
        }
        // ---- defer-max: rescale only if some row grew past THR=8 (log2 units) ----
        bool need = false;
#pragma unroll
        for (int r = 0; r < 4; ++r) need = need || (tm[r] > m_s[r] + 8.f);
        if (__any(need)) {
#pragma unroll
            for (int r = 0; r < 4; ++r) {
                float mn = fmaxf(m_s[r], tm[r]);
                float al = exp2f(m_s[r] - mn);
                l_s[r] *= al;
                m_s[r] = mn;
#pragma unroll
                for (int nd = 0; nd < 4; ++nd) acc_o[nd][r] *= al;
            }
        }

        // ---- p = exp2(s - m), sum, store to BP (overwriting this wave's bias rows) ----
        float ps[4] = {0.f, 0.f, 0.f, 0.f};
#pragma unroll
        for (int ni = 0; ni < 8; ++ni)
#pragma unroll
            for (int r = 0; r < 4; ++r) {
                float p = exp2f(s[ni][r] - m_s[r]);
                ps[r] += p;
                unsigned pb = __float_as_uint(p) + 0x8000u;   // cheap round-half-up
                BP[pr + r][ni * 16 + lr] = (u16)(pb >> 16);
            }
#pragma unroll
        for (int r = 0; r < 4; ++r) {
            float v = ps[r];
            v += __shfl_xor(v, 1);
            v += __shfl_xor(v, 2);
            v += __shfl_xor(v, 4);
            v += __shfl_xor(v, 8);
            l_s[r] += v;
        }

        // ---- PV: P (A-frag from BP rows of this wave) x V^T tile ----
#pragma unroll
        for (int kc = 0; kc < 4; ++kc) {
            bf16x8 pa = *(const bf16x8*)&BP[w * 16 + lr][kc * 32 + lg * 8];
#pragma unroll
            for (int nd = 0; nd < 4; ++nd) {
                bf16x8 bv = *(const bf16x8*)&Vt[nd * 16 + lr][kc * 32 + lg * 8];
                acc_o[nd] = __builtin_amdgcn_mfma_f32_16x16x32_bf16(pa, bv, acc_o[nd], 0, 0, 0);
            }
        }
    }

#pragma unroll
    for (int r = 0; r < 4; ++r) {
        float inv = 1.f / l_s[r];
        int i_g = i0 + w * 16 + lg * 4 + r;
#pragma unroll
        for (int nd = 0; nd < 4; ++nd) {
            int d = nd * 16 + lr;
            attn_out[(size_t)(b * SEQ + i_g) * DM + h * HD + d] = f2bf(acc_o[nd][r] * inv);
        }
    }
}

extern "C" void kernel_launch(void* const* d_in, const int* in_sizes, int n_in,
                              void* d_out, int out_size, void* d_ws, size_t ws_size,
                              hipStream_t stream) {
    const float* q_w    = (const float*)d_in[0];
    const float* q_b    = (const float*)d_in[1];
    const float* k_w    = (const float*)d_in[2];
    const float* k_b    = (const float*)d_in[3];
    const float* v_w    = (const float*)d_in[4];
    const float* v_b    = (const float*)d_in[5];
    const float* o_w    = (const float*)d_in[6];
    const float* o_b    = (const float*)d_in[7];
    const float* emb1_w = (const float*)d_in[8];
    const float* emb1_b = (const float*)d_in[9];
    const float* emb2_w = (const float*)d_in[10];
    const float* emb2_b = (const float*)d_in[11];
    const float* log_w  = (const float*)d_in[12];
    const float* log_b  = (const float*)d_in[13];
    const float* prime_w= (const float*)d_in[14];
    const float* prime_b= (const float*)d_in[15];
    const float* div_w  = (const float*)d_in[16];
    const float* div_b  = (const float*)d_in[17];
    const float* bit_w  = (const float*)d_in[18];
    const float* bit_b  = (const float*)d_in[19];
    const float* fus_w  = (const float*)d_in[20];
    const float* fus_b  = (const float*)d_in[21];
    const float* gcd_weight = (const float*)d_in[23];
    const int*   enc    = (const int*)d_in[24];

    char* ws = (char*)d_ws;
    size_t off = 0;
    auto alloc = [&](size_t bytes) {
        char* p = ws + off;
        off += (bytes + 255) & ~size_t(255);
        return p;
    };
    u16*   WcT    = (u16*)alloc((size_t)DM * KF * 2);
    u16*   WqkvT  = (u16*)alloc((size_t)3072 * DM * 2);
    u16*   WoT    = (u16*)alloc((size_t)DM * DM * 2);
    float* cvec   = (float*)alloc(DM * 4);
    float* qkvb   = (float*)alloc(3072 * 4);
    u16*   F      = (u16*)alloc((size_t)NB * SEQ * KF * 2);
    u16*   hidden = (u16*)alloc((size_t)NB * SEQ * DM * 2);
    u16*   qkv    = (u16*)alloc((size_t)NB * SEQ * LDQKV * 2);
    u16*   vT     = (u16*)alloc((size_t)NB * NH * HD * SEQ * 2);
    u16*   biasM  = (u16*)alloc((size_t)NB * SEQ * SEQ * 2);
    u16*   attn_o = (u16*)alloc((size_t)NB * SEQ * DM * 2);
    (void)ws_size; (void)n_in; (void)in_sizes; (void)out_size;

    // weight prep
    transw_kernel<<<dim3(32, 16), dim3(32, 8), 0, stream>>>(emb2_w, WcT, DM, KF);
    transw_kernel<<<dim3(32, 32), dim3(32, 8), 0, stream>>>(q_w, WqkvT, DM, DM);
    transw_kernel<<<dim3(32, 32), dim3(32, 8), 0, stream>>>(k_w, WqkvT + (size_t)1024 * DM, DM, DM);
    transw_kernel<<<dim3(32, 32), dim3(32, 8), 0, stream>>>(v_w, WqkvT + (size_t)2048 * DM, DM, DM);
    transw_kernel<<<dim3(32, 32), dim3(32, 8), 0, stream>>>(o_w, WoT, DM, DM);
    fold_kernel<<<dim3(4, 64), 256, 0, stream>>>(log_w, prime_w, div_w, bit_w, fus_w, WcT);
    cvec_kernel<<<4, 256, 0, stream>>>(emb2_b, fus_b, log_b, prime_b, div_b, bit_b, fus_w, cvec);
    qkvb_kernel<<<12, 256, 0, stream>>>(q_b, k_b, v_b, qkvb);

    // features + hidden
    feat_kernel<<<NB * SEQ, 256, 0, stream>>>(enc, emb1_w, emb1_b, F);
    gemm_kernel<1><<<dim3(DM / 128, NB * SEQ / 128), 256, 0, stream>>>(F, WcT, cvec, hidden,
                                                                       NB * SEQ, DM, KF);
    // qkv
    gemm_kernel<1><<<dim3(3072 / 128, NB * SEQ / 128), 256, 0, stream>>>(hidden, WqkvT, qkvb, qkv,
                                                                         NB * SEQ, 3072, DM);
    vtrans_kernel<<<dim3(SEQ / 64, NH, NB), 256, 0, stream>>>(qkv, vT);
    biasm_kernel<<<dim3(SEQ / 256, SEQ, NB), 256, 0, stream>>>(enc, gcd_weight, biasM);
    attn_kernel<<<dim3(SEQ / 64, NH, NB), 256, 0, stream>>>(qkv, vT, biasM, attn_o);
    // output projection (fp32 out)
    gemm_kernel<0><<<dim3(DM / 128, NB * SEQ / 128), 256, 0, stream>>>(attn_o, WoT, o_b, d_out,
                                                                       NB * SEQ, DM, DM);
}

// Round 3
// 261.522 us; speedup vs baseline: 1.1282x; 1.1192x over previous
//
#include <hip/hip_runtime.h>
#include <hip/hip_bf16.h>

typedef unsigned short u16;
typedef __attribute__((ext_vector_type(8))) __bf16 bf16x8;
typedef __attribute__((ext_vector_type(4))) float f32x4;

#define SEQ 2048
#define NB 2
#define NH 16
#define HD 64
#define DM 1024
#define LDQKV 3072
#define KF 576   // folded feature K: 512 h1 + 63 feats + 1 pad
#define LOG2E 1.4426950408889634f

__device__ __forceinline__ u16 f2bf(float f) {
    unsigned u = __float_as_uint(f);
    unsigned r = u + 0x7FFFu + ((u >> 16) & 1u);
    return (u16)(r >> 16);
}
__device__ __forceinline__ float bf2f(u16 x) {
    return __uint_as_float(((unsigned)x) << 16);
}
__device__ __forceinline__ unsigned cvt_pk_bf16(float a, float b) {
    unsigned r;
    asm("v_cvt_pk_bf16_f32 %0, %1, %2" : "=v"(r) : "v"(a), "v"(b));
    return r;
}

// ---------------- weight transpose: dst[n*ldd + k] = bf16(src[k*N + n] * scale) ----------
__global__ __launch_bounds__(256) void transw_kernel(const float* __restrict__ src,
                                                     u16* __restrict__ dst, int N, int ldd,
                                                     float scale) {
    __shared__ float tl[32][33];
    int tx = threadIdx.x, ty = threadIdx.y;
    int n = blockIdx.x * 32 + tx;
    int kbase = blockIdx.y * 32;
#pragma unroll
    for (int i = 0; i < 4; ++i)
        tl[ty + i * 8][tx] = src[(size_t)(kbase + ty + i * 8) * N + n];
    __syncthreads();
    int k = kbase + tx;
#pragma unroll
    for (int i = 0; i < 4; ++i) {
        int n2 = blockIdx.x * 32 + ty + i * 8;
        dst[(size_t)n2 * ldd + k] = f2bf(tl[tx][ty + i * 8] * scale);
    }
}

// ---------------- fold small feature weights through fus_w into WcT rows 512..575 ------
__global__ __launch_bounds__(256) void fold_kernel(const float* __restrict__ log_w,
                                                   const float* __restrict__ prime_w,
                                                   const float* __restrict__ div_w,
                                                   const float* __restrict__ bit_w,
                                                   const float* __restrict__ fus_w,
                                                   u16* __restrict__ WcT) {
    const int r = blockIdx.y;  // 0..63
    const int n = blockIdx.x * 256 + threadIdx.x;
    if (r == 63) { WcT[(size_t)n * KF + 575] = 0; return; }
    const float* wrow; int chunk;
    if (r == 0)       { wrow = log_w;                 chunk = 0;   }
    else if (r < 11)  { wrow = prime_w + (r - 1) * 256; chunk = 256; }
    else if (r < 31)  { wrow = div_w + (r - 11) * 256;  chunk = 512; }
    else              { wrow = bit_w + (r - 31) * 256;  chunk = 768; }
    float acc = 0.f;
#pragma unroll 8
    for (int m = 0; m < 256; ++m)
        acc += wrow[m] * fus_w[(size_t)(chunk + m) * DM + n];
    WcT[(size_t)n * KF + 512 + r] = f2bf(acc);
}

// ---------------- constant bias vector for hidden ----------------
__global__ void cvec_kernel(const float* __restrict__ emb2_b, const float* __restrict__ fus_b,
                            const float* __restrict__ log_b, const float* __restrict__ prime_b,
                            const float* __restrict__ div_b, const float* __restrict__ bit_b,
                            const float* __restrict__ fus_w, float* __restrict__ cvec) {
    int n = blockIdx.x * 256 + threadIdx.x;
    float acc = emb2_b[n] + fus_b[n];
#pragma unroll 4
    for (int m = 0; m < 256; ++m) {
        acc += log_b[m]   * fus_w[(size_t)m * DM + n];
        acc += prime_b[m] * fus_w[(size_t)(256 + m) * DM + n];
        acc += div_b[m]   * fus_w[(size_t)(512 + m) * DM + n];
        acc += bit_b[m]   * fus_w[(size_t)(768 + m) * DM + n];
    }
    cvec[n] = acc;
}

__global__ void qkvb_kernel(const float* __restrict__ q_b, const float* __restrict__ k_b,
                            const float* __restrict__ v_b, float* __restrict__ qkvb) {
    int i = blockIdx.x * 256 + threadIdx.x;  // 0..3071
    const float C1 = 0.125f * LOG2E;
    qkvb[i] = (i < 1024) ? q_b[i] * C1 : (i < 2048 ? k_b[i - 1024] : v_b[i - 2048]);
}

// ---------------- per-token feature vector F (4096 x 576 bf16) ----------------
__global__ __launch_bounds__(256) void feat_kernel(const int* __restrict__ enc,
                                                   const float* __restrict__ emb1_w,
                                                   const float* __restrict__ emb1_b,
                                                   u16* __restrict__ F) {
    const int tok = blockIdx.x;
    const int t = threadIdx.x;
    int e = enc[tok];
    float ef = (float)e;
    float nrm = ef / 2147483647.0f;
    for (int k = t; k < 512; k += 256)
        F[(size_t)tok * KF + k] = f2bf(fmaxf(nrm * emb1_w[k] + emb1_b[k], 0.f));
    if (t < 64) {
        float v;
        if (t == 0) v = logf(ef + 1.f);
        else if (t < 11) {
            const int pr[10] = {2, 3, 5, 7, 11, 13, 17, 19, 23, 29};
            v = (e % pr[t - 1] == 0) ? 1.f : 0.f;
        } else if (t < 31) {
            int tv = t - 11 + 2;
            v = (float)(e % tv) / (float)tv;
        } else if (t < 63) {
            int sh = t - 31;
            v = (float)((e >> sh) & 1);
        } else v = 0.f;
        F[(size_t)tok * KF + 512 + t] = f2bf(v);
    }
}

// ---------------- GEMM: C[MxN] = A(bf16 MxK) @ BT(bf16 NxK)^T + bias ----------------
template <int OUT_BF16>
__global__ __launch_bounds__(256) void gemm_kernel(const u16* __restrict__ A,
                                                   const u16* __restrict__ BT,
                                                   const float* __restrict__ bias,
                                                   void* __restrict__ Cv,
                                                   int M, int N, int K) {
    __shared__ u16 As[128][40];
    __shared__ u16 Bs[128][40];
    const int t = threadIdx.x;
    const int m0 = blockIdx.y * 128, n0 = blockIdx.x * 128;
    const int w = t >> 6, l = t & 63, lr = l & 15, lg = l >> 4;
    const int wm = (w >> 1) * 64, wn = (w & 1) * 64;
    f32x4 acc[4][4] = {};
    const int ar = t >> 1, ac = (t & 1) * 16;
    for (int k0 = 0; k0 < K; k0 += 32) {
        __syncthreads();
        {
            const int4* ga = (const int4*)&A[(size_t)(m0 + ar) * K + k0 + ac];
            int4 v0 = ga[0], v1 = ga[1];
            *(int4*)&As[ar][ac] = v0;
            *(int4*)&As[ar][ac + 8] = v1;
            const int4* gb = (const int4*)&BT[(size_t)(n0 + ar) * K + k0 + ac];
            int4 u0 = gb[0], u1 = gb[1];
            *(int4*)&Bs[ar][ac] = u0;
            *(int4*)&Bs[ar][ac + 8] = u1;
        }
        __syncthreads();
        bf16x8 a[4], b[4];
#pragma unroll
        for (int i = 0; i < 4; ++i) a[i] = *(const bf16x8*)&As[wm + i * 16 + lr][lg * 8];
#pragma unroll
        for (int i = 0; i < 4; ++i) b[i] = *(const bf16x8*)&Bs[wn + i * 16 + lr][lg * 8];
#pragma unroll
        for (int mi = 0; mi < 4; ++mi)
#pragma unroll
            for (int ni = 0; ni < 4; ++ni)
                acc[mi][ni] = __builtin_amdgcn_mfma_f32_16x16x32_bf16(a[mi], b[ni], acc[mi][ni], 0, 0, 0);
    }
#pragma unroll
    for (int mi = 0; mi < 4; ++mi)
#pragma unroll
        for (int ni = 0; ni < 4; ++ni)
#pragma unroll
            for (int r = 0; r < 4; ++r) {
                int row = m0 + wm + mi * 16 + lg * 4 + r;
                int col = n0 + wn + ni * 16 + lr;
                float v = acc[mi][ni][r] + bias[col];
                if (OUT_BF16)
                    ((u16*)Cv)[(size_t)row * N + col] = f2bf(v);
                else
                    ((float*)Cv)[(size_t)row * N + col] = v;
            }
}

// ---------------- V transpose: vT[b][h][d][s] = v[b][s][h][d] ----------------
__global__ __launch_bounds__(256) void vtrans_kernel(const u16* __restrict__ qkv,
                                                     u16* __restrict__ vT) {
    __shared__ u16 tile[64][72];
    int t = threadIdx.x;
    int s0 = blockIdx.x * 64, h = blockIdx.y, b = blockIdx.z;
    int sr = t >> 2, sc = (t & 3) * 16;
    const int4* g = (const int4*)&qkv[(size_t)(b * SEQ + s0 + sr) * LDQKV + 2048 + h * HD + sc];
    int4 v0 = g[0], v1 = g[1];
    *(int4*)&tile[sr][sc] = v0;
    *(int4*)&tile[sr][sc + 8] = v1;
    __syncthreads();
    int dl = sr, j0 = sc;
    u16 tmp[16];
#pragma unroll
    for (int jj = 0; jj < 16; ++jj) tmp[jj] = tile[j0 + jj][dl];
    u16* out = &vT[(size_t)((b * NH + h) * HD + dl) * SEQ + s0 + j0];
    *(int4*)&out[0] = *(int4*)&tmp[0];
    *(int4*)&out[8] = *(int4*)&tmp[8];
}

// ---------------- gcd-ish bias matrix (B,S,S) bf16, pre-scaled by gcd_w*log2(e) --------
__global__ __launch_bounds__(256) void biasm_kernel(const int* __restrict__ enc,
                                                    const float* __restrict__ gcd_w,
                                                    u16* __restrict__ biasM) {
    int j = blockIdx.x * 256 + threadIdx.x;
    int i = blockIdx.y;
    int b = blockIdx.z;
    unsigned ei = (unsigned)enc[b * SEQ + i];
    unsigned ej = (unsigned)enc[b * SEQ + j];
    unsigned r1 = ei % (ej + 1u);
    unsigned r2 = ej % (ei + 1u);
    unsigned g = min(r1, r2);
    unsigned mx = max(ei, ej) + 1u;
    float v = (i == j) ? 0.f : (float)g / (float)mx;
    biasM[((size_t)b * SEQ + i) * SEQ + j] = f2bf(v * (gcd_w[0] * LOG2E));
}

// ---------------- fused attention: swapped-operand S^T flash, KVB=64 ----------------
// S^T = mfma(K, Q) with C initialized to bias (global loads, symmetric layout match).
// LDS tiles are linear 128B rows with XOR swizzle byte ^= (row&7)<<4.
#define KVB 64
#define SWZ(row, cb) ((((int)(row)) << 7) + (((int)(cb)) ^ ((((int)(row)) & 7) << 4)))

__global__ __launch_bounds__(256) void attn_kernel(const u16* __restrict__ qkv,
                                                   const u16* __restrict__ vT,
                                                   const u16* __restrict__ biasM,
                                                   u16* __restrict__ attn_out) {
    __shared__ char smem[24576];   // Kt 8KB | Vt 8KB | Pl 4x2KB
    char* KtB = smem;
    char* VtB = smem + 8192;
    const int t = threadIdx.x, w = t >> 6, l = t & 63, lr = l & 15, lg = l >> 4;
    char* PlB = smem + 16384 + (w << 11);
    const int qt = blockIdx.x, h = blockIdx.y, b = blockIdx.z;
    const int i0 = qt * 64;
    const int qrow = i0 + w * 16 + lr;

    // Q fragment (B-operand): col=q=lr, k=d (Q pre-scaled by 0.125*log2e)
    bf16x8 qf[2];
#pragma unroll
    for (int kk = 0; kk < 2; ++kk)
        qf[kk] = *(const bf16x8*)&qkv[(size_t)(b * SEQ + qrow) * LDQKV + h * HD + kk * 32 + lg * 8];

    // staging addresses: row sr = t>>2 (0..63), col sc = (t&3)*16 u16
    const int sr = t >> 2, sc = (t & 3) * 16;
    const u16* gK = &qkv[(size_t)(b * SEQ + sr) * LDQKV + 1024 + h * HD + sc];
    const u16* gV = &vT[(size_t)((b * NH + h) * HD + sr) * SEQ + sc];
    const u16* gB = &biasM[((size_t)b * SEQ + qrow) * SEQ + lg * 4];

    // prologue: prefetch tile 0 into regs
    int4 kr0 = *(const int4*)&gK[0], kr1 = *(const int4*)&gK[8];
    int4 vr0 = *(const int4*)&gV[0], vr1 = *(const int4*)&gV[8];
    int2 br[4];
#pragma unroll
    for (int ni = 0; ni < 4; ++ni) br[ni] = *(const int2*)&gB[ni * 16];

    float m_s = -1e30f, l_s = 0.f;
    f32x4 acc_o[4] = {};

    for (int jt = 0; jt < SEQ / KVB; ++jt) {
        __syncthreads();
        // write staged regs -> LDS (swizzled)
        *(int4*)(KtB + SWZ(sr, (t & 3) * 32))      = kr0;
        *(int4*)(KtB + SWZ(sr, (t & 3) * 32 + 16)) = kr1;
        *(int4*)(VtB + SWZ(sr, (t & 3) * 32))      = vr0;
        *(int4*)(VtB + SWZ(sr, (t & 3) * 32 + 16)) = vr1;
        __syncthreads();

        // C-init from bias regs: s[ni][r] = bias(kv = ni*16+lg*4+r, q = lr)
        f32x4 s[4];
#pragma unroll
        for (int ni = 0; ni < 4; ++ni) {
            unsigned d0 = (unsigned)br[ni].x, d1 = (unsigned)br[ni].y;
            s[ni][0] = __uint_as_float(d0 << 16);
            s[ni][1] = __uint_as_float(d0 & 0xFFFF0000u);
            s[ni][2] = __uint_as_float(d1 << 16);
            s[ni][3] = __uint_as_float(d1 & 0xFFFF0000u);
        }
        // async prefetch of next tile (overlaps compute)
        if (jt < SEQ / KVB - 1) {
            const int jb2 = (jt + 1) * KVB;
            kr0 = *(const int4*)&gK[(size_t)jb2 * LDQKV];
            kr1 = *(const int4*)&gK[(size_t)jb2 * LDQKV + 8];
            vr0 = *(const int4*)&gV[jb2];
            vr1 = *(const int4*)&gV[jb2 + 8];
#pragma unroll
            for (int ni = 0; ni < 4; ++ni) br[ni] = *(const int2*)&gB[jb2 + ni * 16];
        }

        // S^T = K @ Q^T (+bias in C): s[ni] rows kv=ni*16+lg*4+r, col q=lr
#pragma unroll
        for (int kk = 0; kk < 2; ++kk)
#pragma unroll
            for (int ni = 0; ni < 4; ++ni) {
                bf16x8 kf = *(const bf16x8*)(KtB + SWZ(ni * 16 + lr, kk * 64 + lg * 16));
                s[ni] = __builtin_amdgcn_mfma_f32_16x16x32_bf16(kf, qf[kk], s[ni], 0, 0, 0);
            }

        // softmax over kv (16 in-lane + lanes l^16, l^32), log2 domain
        float tm = s[0][0];
#pragma unroll
        for (int ni = 0; ni < 4; ++ni)
#pragma unroll
            for (int r = 0; r < 4; ++r) tm = fmaxf(tm, s[ni][r]);
        tm = fmaxf(tm, __shfl_xor(tm, 16));
        tm = fmaxf(tm, __shfl_xor(tm, 32));

        if (__any(tm > m_s + 8.f)) {
            float mn = fmaxf(m_s, tm);
            float al = __builtin_exp2f(m_s - mn);
            l_s *= al;
            m_s = mn;
#pragma unroll
            for (int nd = 0; nd < 4; ++nd)
#pragma unroll
                for (int r = 0; r < 4; ++r) acc_o[nd][r] *= al;
        }

        float ps = 0.f;
#pragma unroll
        for (int ni = 0; ni < 4; ++ni)
#pragma unroll
            for (int r = 0; r < 4; ++r) {
                float p = __builtin_exp2f(s[ni][r] - m_s);
                s[ni][r] = p;
                ps += p;
            }
        ps += __shfl_xor(ps, 16);
        ps += __shfl_xor(ps, 32);
        l_s += ps;

        // pack P^T into per-wave LDS: Pl[q=lr][kv], b64 writes
#pragma unroll
        for (int ni = 0; ni < 4; ++ni) {
            uint2 u;
            u.x = cvt_pk_bf16(s[ni][0], s[ni][1]);
            u.y = cvt_pk_bf16(s[ni][2], s[ni][3]);
            *(uint2*)(PlB + SWZ(lr, ni * 32 + lg * 8)) = u;
        }
        asm volatile("s_waitcnt lgkmcnt(0)" ::: "memory");
        __builtin_amdgcn_sched_barrier(0);

        // PV: O^T = V^T @ P^T : acc_o[nd] rows d=nd*16+lg*4+r, col q=lr
#pragma unroll
        for (int kc = 0; kc < 2; ++kc) {
            bf16x8 pf = *(const bf16x8*)(PlB + SWZ(lr, kc * 64 + lg * 16));
#pragma unroll
            for (int nd = 0; nd < 4; ++nd) {
                bf16x8 vf = *(const bf16x8*)(VtB + SWZ(nd * 16 + lr, kc * 64 + lg * 16));
                acc_o[nd] = __builtin_amdgcn_mfma_f32_16x16x32_bf16(vf, pf, acc_o[nd], 0, 0, 0);
            }
        }
    }

    // epilogue: O^T lane holds d=nd*16+lg*4+r for q=lr; write dwordx2 per nd
    float inv = 1.f / l_s;
    u16* orow = &attn_out[(size_t)(b * SEQ + qrow) * DM + h * HD];
#pragma unroll
    for (int nd = 0; nd < 4; ++nd) {
        uint2 u;
        u.x = cvt_pk_bf16(acc_o[nd][0] * inv, acc_o[nd][1] * inv);
        u.y = cvt_pk_bf16(acc_o[nd][2] * inv, acc_o[nd][3] * inv);
        *(uint2*)&orow[nd * 16 + lg * 4] = u;
    }
}

extern "C" void kernel_launch(void* const* d_in, const int* in_sizes, int n_in,
                              void* d_out, int out_size, void* d_ws, size_t ws_size,
                              hipStream_t stream) {
    const float* q_w    = (const float*)d_in[0];
    const float* q_b    = (const float*)d_in[1];
    const float* k_w    = (const float*)d_in[2];
    const float* k_b    = (const float*)d_in[3];
    const float* v_w    = (const float*)d_in[4];
    const float* v_b    = (const float*)d_in[5];
    const float* o_w    = (const float*)d_in[6];
    const float* o_b    = (const float*)d_in[7];
    const float* emb1_w = (const float*)d_in[8];
    const float* emb1_b = (const float*)d_in[9];
    const float* emb2_w = (const float*)d_in[10];
    const float* emb2_b = (const float*)d_in[11];
    const float* log_w  = (const float*)d_in[12];
    const float* log_b  = (const float*)d_in[13];
    const float* prime_w= (const float*)d_in[14];
    const float* prime_b= (const float*)d_in[15];
    const float* div_w  = (const float*)d_in[16];
    const float* div_b  = (const float*)d_in[17];
    const float* bit_w  = (const float*)d_in[18];
    const float* bit_b  = (const float*)d_in[19];
    const float* fus_w  = (const float*)d_in[20];
    const float* fus_b  = (const float*)d_in[21];
    const float* gcd_weight = (const float*)d_in[23];
    const int*   enc    = (const int*)d_in[24];

    char* ws = (char*)d_ws;
    size_t off = 0;
    auto alloc = [&](size_t bytes) {
        char* p = ws + off;
        off += (bytes + 255) & ~size_t(255);
        return p;
    };
    u16*   WcT    = (u16*)alloc((size_t)DM * KF * 2);
    u16*   WqkvT  = (u16*)alloc((size_t)3072 * DM * 2);
    u16*   WoT    = (u16*)alloc((size_t)DM * DM * 2);
    float* cvec   = (float*)alloc(DM * 4);
    float* qkvb   = (float*)alloc(3072 * 4);
    u16*   F      = (u16*)alloc((size_t)NB * SEQ * KF * 2);
    u16*   hidden = (u16*)alloc((size_t)NB * SEQ * DM * 2);
    u16*   qkv    = (u16*)alloc((size_t)NB * SEQ * LDQKV * 2);
    u16*   vT     = (u16*)alloc((size_t)NB * NH * HD * SEQ * 2);
    u16*   biasM  = (u16*)alloc((size_t)NB * SEQ * SEQ * 2);
    u16*   attn_o = (u16*)alloc((size_t)NB * SEQ * DM * 2);
    (void)ws_size; (void)n_in; (void)in_sizes; (void)out_size;

    const float C1 = 0.125f * LOG2E;
    // weight prep (q_w pre-scaled so scores come out in log2 domain)
    transw_kernel<<<dim3(32, 16), dim3(32, 8), 0, stream>>>(emb2_w, WcT, DM, KF, 1.0f);
    transw_kernel<<<dim3(32, 32), dim3(32, 8), 0, stream>>>(q_w, WqkvT, DM, DM, C1);
    transw_kernel<<<dim3(32, 32), dim3(32, 8), 0, stream>>>(k_w, WqkvT + (size_t)1024 * DM, DM, DM, 1.0f);
    transw_kernel<<<dim3(32, 32), dim3(32, 8), 0, stream>>>(v_w, WqkvT + (size_t)2048 * DM, DM, DM, 1.0f);
    transw_kernel<<<dim3(32, 32), dim3(32, 8), 0, stream>>>(o_w, WoT, DM, DM, 1.0f);
    fold_kernel<<<dim3(4, 64), 256, 0, stream>>>(log_w, prime_w, div_w, bit_w, fus_w, WcT);
    cvec_kernel<<<4, 256, 0, stream>>>(emb2_b, fus_b, log_b, prime_b, div_b, bit_b, fus_w, cvec);
    qkvb_kernel<<<12, 256, 0, stream>>>(q_b, k_b, v_b, qkvb);

    // features + hidden
    feat_kernel<<<NB * SEQ, 256, 0, stream>>>(enc, emb1_w, emb1_b, F);
    gemm_kernel<1><<<dim3(DM / 128, NB * SEQ / 128), 256, 0, stream>>>(F, WcT, cvec, hidden,
                                                                       NB * SEQ, DM, KF);
    // qkv
    gemm_kernel<1><<<dim3(3072 / 128, NB * SEQ / 128), 256, 0, stream>>>(hidden, WqkvT, qkvb, qkv,
                                                                         NB * SEQ, 3072, DM);
    vtrans_kernel<<<dim3(SEQ / 64, NH, NB), 256, 0, stream>>>(qkv, vT);
    biasm_kernel<<<dim3(SEQ / 256, SEQ, NB), 256, 0, stream>>>(enc, gcd_weight, biasM);
    attn_kernel<<<dim3(SEQ / 64, NH, NB), 256, 0, stream>>>(qkv, vT, biasM, attn_o);
    // output projection (fp32 out)
    gemm_kernel<0><<<dim3(DM / 128, NB * SEQ / 128), 256, 0, stream>>>(attn_o, WoT, o_b, d_out,
                                                                       NB * SEQ, DM, DM);
}

// Round 4
// 243.588 us; speedup vs baseline: 1.2112x; 1.0736x over previous
//
#include <hip/hip_runtime.h>
#include <hip/hip_bf16.h>

typedef unsigned short u16;
typedef __attribute__((ext_vector_type(8))) __bf16 bf16x8;
typedef __attribute__((ext_vector_type(4))) float f32x4;

#define SEQ 2048
#define NB 2
#define NH 16
#define HD 64
#define DM 1024
#define LDQKV 3072
#define KF 576   // folded feature K: 512 h1 + 63 feats + 1 pad
#define LOG2E 1.4426950408889634f

__device__ __forceinline__ u16 f2bf(float f) {
    unsigned u = __float_as_uint(f);
    unsigned r = u + 0x7FFFu + ((u >> 16) & 1u);
    return (u16)(r >> 16);
}
__device__ __forceinline__ unsigned cvt_pk_bf16(float a, float b) {
    unsigned r;
    asm("v_cvt_pk_bf16_f32 %0, %1, %2" : "=v"(r) : "v"(a), "v"(b));
    return r;
}
// async global->LDS DMA, 16B per lane; ldst must be wave-uniform, writes at +lane*16B
__device__ __forceinline__ void gl_lds16(const u16* g, u16* l) {
    __builtin_amdgcn_global_load_lds((const __attribute__((address_space(1))) unsigned int*)g,
                                     (__attribute__((address_space(3))) unsigned int*)l, 16, 0, 0);
}

// ---------------- weight transpose: dst[n*ldd + k] = bf16(src[k*N + n] * scale) ----------
__global__ __launch_bounds__(256) void transw_kernel(const float* __restrict__ src,
                                                     u16* __restrict__ dst, int N, int ldd,
                                                     float scale) {
    __shared__ float tl[32][33];
    int tx = threadIdx.x, ty = threadIdx.y;
    int n = blockIdx.x * 32 + tx;
    int kbase = blockIdx.y * 32;
#pragma unroll
    for (int i = 0; i < 4; ++i)
        tl[ty + i * 8][tx] = src[(size_t)(kbase + ty + i * 8) * N + n];
    __syncthreads();
    int k = kbase + tx;
#pragma unroll
    for (int i = 0; i < 4; ++i) {
        int n2 = blockIdx.x * 32 + ty + i * 8;
        dst[(size_t)n2 * ldd + k] = f2bf(tl[tx][ty + i * 8] * scale);
    }
}

// ---------------- fold small feature weights through fus_w into WcT rows 512..575 ------
__global__ __launch_bounds__(256) void fold_kernel(const float* __restrict__ log_w,
                                                   const float* __restrict__ prime_w,
                                                   const float* __restrict__ div_w,
                                                   const float* __restrict__ bit_w,
                                                   const float* __restrict__ fus_w,
                                                   u16* __restrict__ WcT) {
    const int r = blockIdx.y;  // 0..63
    const int n = blockIdx.x * 256 + threadIdx.x;
    if (r == 63) { WcT[(size_t)n * KF + 575] = 0; return; }
    const float* wrow; int chunk;
    if (r == 0)       { wrow = log_w;                 chunk = 0;   }
    else if (r < 11)  { wrow = prime_w + (r - 1) * 256; chunk = 256; }
    else if (r < 31)  { wrow = div_w + (r - 11) * 256;  chunk = 512; }
    else              { wrow = bit_w + (r - 31) * 256;  chunk = 768; }
    float acc = 0.f;
#pragma unroll 8
    for (int m = 0; m < 256; ++m)
        acc += wrow[m] * fus_w[(size_t)(chunk + m) * DM + n];
    WcT[(size_t)n * KF + 512 + r] = f2bf(acc);
}

// ---------------- constant bias vector for hidden ----------------
__global__ void cvec_kernel(const float* __restrict__ emb2_b, const float* __restrict__ fus_b,
                            const float* __restrict__ log_b, const float* __restrict__ prime_b,
                            const float* __restrict__ div_b, const float* __restrict__ bit_b,
                            const float* __restrict__ fus_w, float* __restrict__ cvec) {
    int n = blockIdx.x * 256 + threadIdx.x;
    float acc = emb2_b[n] + fus_b[n];
#pragma unroll 4
    for (int m = 0; m < 256; ++m) {
        acc += log_b[m]   * fus_w[(size_t)m * DM + n];
        acc += prime_b[m] * fus_w[(size_t)(256 + m) * DM + n];
        acc += div_b[m]   * fus_w[(size_t)(512 + m) * DM + n];
        acc += bit_b[m]   * fus_w[(size_t)(768 + m) * DM + n];
    }
    cvec[n] = acc;
}

__global__ void qkvb_kernel(const float* __restrict__ q_b, const float* __restrict__ k_b,
                            const float* __restrict__ v_b, float* __restrict__ qkvb) {
    int i = blockIdx.x * 256 + threadIdx.x;  // 0..3071
    const float C1 = 0.125f * LOG2E;
    qkvb[i] = (i < 1024) ? q_b[i] * C1 : (i < 2048 ? k_b[i - 1024] : v_b[i - 2048]);
}

// ---------------- per-token feature vector F (4096 x 576 bf16) ----------------
__global__ __launch_bounds__(256) void feat_kernel(const int* __restrict__ enc,
                                                   const float* __restrict__ emb1_w,
                                                   const float* __restrict__ emb1_b,
                                                   u16* __restrict__ F) {
    const int tok = blockIdx.x;
    const int t = threadIdx.x;
    int e = enc[tok];
    float ef = (float)e;
    float nrm = ef / 2147483647.0f;
    for (int k = t; k < 512; k += 256)
        F[(size_t)tok * KF + k] = f2bf(fmaxf(nrm * emb1_w[k] + emb1_b[k], 0.f));
    if (t < 64) {
        float v;
        if (t == 0) v = logf(ef + 1.f);
        else if (t < 11) {
            const int pr[10] = {2, 3, 5, 7, 11, 13, 17, 19, 23, 29};
            v = (e % pr[t - 1] == 0) ? 1.f : 0.f;
        } else if (t < 31) {
            int tv = t - 11 + 2;
            v = (float)(e % tv) / (float)tv;
        } else if (t < 63) {
            int sh = t - 31;
            v = (float)((e >> sh) & 1);
        } else v = 0.f;
        F[(size_t)tok * KF + 512 + t] = f2bf(v);
    }
}

// ---------------- GEMM (m97 structure): C[M x N] = A @ BT^T + bias ----------------
// TM=128 fixed; TN in {128, 64}. Linear LDS [rows][32], staged via global_load_lds.
template <int OUT_BF16, int TN>
__global__ __launch_bounds__(256) void gemm_kernel(const u16* __restrict__ A,
                                                   const u16* __restrict__ BT,
                                                   const float* __restrict__ bias,
                                                   void* __restrict__ Cv,
                                                   int M, int N, int K) {
    constexpr int FN = TN / 32;             // 4 or 2 n-fragments per wave
    __shared__ u16 As[128 * 32];
    __shared__ u16 Bs[TN * 32];
    const int t = threadIdx.x;
    const int w = t >> 6, l = t & 63, lr = l & 15, lg = l >> 4;
    const int m0 = blockIdx.y * 128, n0 = blockIdx.x * TN;
    const int wm = (w >> 1) * 64, wn = (w & 1) * (TN / 2);
    const int srow = l >> 2, scol = (l & 3) * 8;

    const u16* gA = &A[(size_t)(m0 + w * 32 + srow) * K + scol];
    u16* lA = &As[w * 1024];
    const u16* gB;
    u16* lB;
    if (TN == 128) { gB = &BT[(size_t)(n0 + w * 32 + srow) * K + scol]; lB = &Bs[w * 1024]; }
    else           { gB = &BT[(size_t)(n0 + w * 16 + srow) * K + scol]; lB = &Bs[w * 512];  }

    f32x4 acc[4][FN] = {};
    for (int k0 = 0; k0 < K; k0 += 32) {
        __syncthreads();
        gl_lds16(gA + k0, lA);
        gl_lds16(gA + k0 + (size_t)16 * K, lA + 512);
        if (TN == 128) {
            gl_lds16(gB + k0, lB);
            gl_lds16(gB + k0 + (size_t)16 * K, lB + 512);
        } else {
            gl_lds16(gB + k0, lB);
        }
        __syncthreads();
        bf16x8 a[4], b[FN];
#pragma unroll
        for (int i = 0; i < 4; ++i) a[i] = *(const bf16x8*)&As[(wm + i * 16 + lr) * 32 + lg * 8];
#pragma unroll
        for (int j = 0; j < FN; ++j) b[j] = *(const bf16x8*)&Bs[(wn + j * 16 + lr) * 32 + lg * 8];
#pragma unroll
        for (int mi = 0; mi < 4; ++mi)
#pragma unroll
            for (int ni = 0; ni < FN; ++ni)
                acc[mi][ni] = __builtin_amdgcn_mfma_f32_16x16x32_bf16(a[mi], b[ni], acc[mi][ni], 0, 0, 0);
    }
#pragma unroll
    for (int mi = 0; mi < 4; ++mi)
#pragma unroll
        for (int ni = 0; ni < FN; ++ni)
#pragma unroll
            for (int r = 0; r < 4; ++r) {
                int row = m0 + wm + mi * 16 + lg * 4 + r;
                int col = n0 + wn + ni * 16 + lr;
                float v = acc[mi][ni][r] + bias[col];
                if (OUT_BF16)
                    ((u16*)Cv)[(size_t)row * N + col] = f2bf(v);
                else
                    ((float*)Cv)[(size_t)row * N + col] = v;
            }
}

// ---------------- V transpose: vT[b][h][d][s] = v[b][s][h][d] ----------------
__global__ __launch_bounds__(256) void vtrans_kernel(const u16* __restrict__ qkv,
                                                     u16* __restrict__ vT) {
    __shared__ u16 tile[64][72];
    int t = threadIdx.x;
    int s0 = blockIdx.x * 64, h = blockIdx.y, b = blockIdx.z;
    int sr = t >> 2, sc = (t & 3) * 16;
    const int4* g = (const int4*)&qkv[(size_t)(b * SEQ + s0 + sr) * LDQKV + 2048 + h * HD + sc];
    int4 v0 = g[0], v1 = g[1];
    *(int4*)&tile[sr][sc] = v0;
    *(int4*)&tile[sr][sc + 8] = v1;
    __syncthreads();
    int dl = sr, j0 = sc;
    u16 tmp[16];
#pragma unroll
    for (int jj = 0; jj < 16; ++jj) tmp[jj] = tile[j0 + jj][dl];
    u16* out = &vT[(size_t)((b * NH + h) * HD + dl) * SEQ + s0 + j0];
    *(int4*)&out[0] = *(int4*)&tmp[0];
    *(int4*)&out[8] = *(int4*)&tmp[8];
}

// ---------------- gcd-ish bias matrix (B,S,S) fp32, pre-scaled by gcd_w*log2(e) --------
__global__ __launch_bounds__(256) void biasm_kernel(const int* __restrict__ enc,
                                                    const float* __restrict__ gcd_w,
                                                    float* __restrict__ biasMf) {
    int j = blockIdx.x * 256 + threadIdx.x;
    int i = blockIdx.y;
    int b = blockIdx.z;
    unsigned ei = (unsigned)enc[b * SEQ + i];
    unsigned ej = (unsigned)enc[b * SEQ + j];
    unsigned r1 = ei % (ej + 1u);
    unsigned r2 = ej % (ei + 1u);
    unsigned g = min(r1, r2);
    unsigned mx = max(ei, ej) + 1u;
    float v = (i == j) ? 0.f : (float)g / (float)mx;
    biasMf[((size_t)b * SEQ + i) * SEQ + j] = v * (gcd_w[0] * LOG2E);
}

// ---------------- fused attention: swapped-operand S^T flash, KVB=64 ----------------
// Double-buffered K/V LDS, ONE barrier per tile. Bias enters as MFMA C-init (fp32 loads).
#define KVB 64
#define SWZ(row, cb) ((((int)(row)) << 7) + (((int)(cb)) ^ ((((int)(row)) & 7) << 4)))

__global__ __launch_bounds__(256) void attn_kernel(const u16* __restrict__ qkv,
                                                   const u16* __restrict__ vT,
                                                   const float* __restrict__ biasMf,
                                                   u16* __restrict__ attn_out) {
    __shared__ char smem[40960];   // [2][Kt 8KB | Vt 8KB] | Pl 4 x 2KB
    const int t = threadIdx.x, w = t >> 6, l = t & 63, lr = l & 15, lg = l >> 4;
    char* PlB = smem + 32768 + (w << 11);
    const int qt = blockIdx.x, h = blockIdx.y, b = blockIdx.z;
    const int qrow = qt * 64 + w * 16 + lr;

    // Q fragment (B-operand): col=q=lr, k=d (Q pre-scaled by 0.125*log2e)
    bf16x8 qf[2];
#pragma unroll
    for (int kk = 0; kk < 2; ++kk)
        qf[kk] = *(const bf16x8*)&qkv[(size_t)(b * SEQ + qrow) * LDQKV + h * HD + kk * 32 + lg * 8];

    const int sr = t >> 2, sc = (t & 3) * 16;
    const u16* gK = &qkv[(size_t)(b * SEQ + sr) * LDQKV + 1024 + h * HD + sc];
    const u16* gV = &vT[(size_t)((b * NH + h) * HD + sr) * SEQ + sc];
    const float* gB = &biasMf[((size_t)b * SEQ + qrow) * SEQ + lg * 4];

    // prologue: prefetch tile 0 into regs
    int4 kr0 = *(const int4*)&gK[0], kr1 = *(const int4*)&gK[8];
    int4 vr0 = *(const int4*)&gV[0], vr1 = *(const int4*)&gV[8];
    f32x4 br[4];
#pragma unroll
    for (int ni = 0; ni < 4; ++ni) br[ni] = *(const f32x4*)&gB[ni * 16];

    float m_s = -1e30f, l_s = 0.f;
    f32x4 acc_o[4] = {};

    for (int jt = 0; jt < SEQ / KVB; ++jt) {
        char* KtB = smem + (jt & 1) * 16384;
        char* VtB = KtB + 8192;
        // write staged regs -> LDS buf c (swizzled)
        *(int4*)(KtB + SWZ(sr, (t & 3) * 32))      = kr0;
        *(int4*)(KtB + SWZ(sr, (t & 3) * 32 + 16)) = kr1;
        *(int4*)(VtB + SWZ(sr, (t & 3) * 32))      = vr0;
        *(int4*)(VtB + SWZ(sr, (t & 3) * 32 + 16)) = vr1;
        // issue K/V prefetch for jt+1 (lands during compute)
        const int jb2 = (jt + 1) * KVB;
        if (jt < SEQ / KVB - 1) {
            kr0 = *(const int4*)&gK[(size_t)jb2 * LDQKV];
            kr1 = *(const int4*)&gK[(size_t)jb2 * LDQKV + 8];
            vr0 = *(const int4*)&gV[jb2];
            vr1 = *(const int4*)&gV[jb2 + 8];
        }
        __syncthreads();

        // C-init from fp32 bias regs: s[ni][r] = bias(kv = ni*16+lg*4+r, q = lr)
        f32x4 s[4];
#pragma unroll
        for (int ni = 0; ni < 4; ++ni) s[ni] = br[ni];
        // issue bias prefetch for jt+1 (after br consumed)
        if (jt < SEQ / KVB - 1) {
#pragma unroll
            for (int ni = 0; ni < 4; ++ni) br[ni] = *(const f32x4*)&gB[jb2 + ni * 16];
        }

        // S^T = K @ Q^T (+bias in C): s[ni] rows kv=ni*16+lg*4+r, col q=lr
#pragma unroll
        for (int kk = 0; kk < 2; ++kk)
#pragma unroll
            for (int ni = 0; ni < 4; ++ni) {
                bf16x8 kf = *(const bf16x8*)(KtB + SWZ(ni * 16 + lr, kk * 64 + lg * 16));
                s[ni] = __builtin_amdgcn_mfma_f32_16x16x32_bf16(kf, qf[kk], s[ni], 0, 0, 0);
            }

        // softmax over kv (16 in-lane + lanes l^16, l^32), log2 domain
        float tm = s[0][0];
#pragma unroll
        for (int ni = 0; ni < 4; ++ni)
#pragma unroll
            for (int r = 0; r < 4; ++r) tm = fmaxf(tm, s[ni][r]);
        tm = fmaxf(tm, __shfl_xor(tm, 16));
        tm = fmaxf(tm, __shfl_xor(tm, 32));

        if (__any(tm > m_s + 8.f)) {
            float mn = fmaxf(m_s, tm);
            float al = __builtin_exp2f(m_s - mn);
            l_s *= al;
            m_s = mn;
#pragma unroll
            for (int nd = 0; nd < 4; ++nd)
#pragma unroll
                for (int r = 0; r < 4; ++r) acc_o[nd][r] *= al;
        }

        float ps = 0.f;
#pragma unroll
        for (int ni = 0; ni < 4; ++ni)
#pragma unroll
            for (int r = 0; r < 4; ++r) {
                float p = __builtin_exp2f(s[ni][r] - m_s);
                s[ni][r] = p;
                ps += p;
            }
        ps += __shfl_xor(ps, 16);
        ps += __shfl_xor(ps, 32);
        l_s += ps;

        // pack P^T into per-wave LDS: Pl[q=lr][kv], b64 writes
#pragma unroll
        for (int ni = 0; ni < 4; ++ni) {
            uint2 u;
            u.x = cvt_pk_bf16(s[ni][0], s[ni][1]);
            u.y = cvt_pk_bf16(s[ni][2], s[ni][3]);
            *(uint2*)(PlB + SWZ(lr, ni * 32 + lg * 8)) = u;
        }
        asm volatile("s_waitcnt lgkmcnt(0)" ::: "memory");
        __builtin_amdgcn_sched_barrier(0);

        // PV: O^T = V^T @ P^T : acc_o[nd] rows d=nd*16+lg*4+r, col q=lr
#pragma unroll
        for (int kc = 0; kc < 2; ++kc) {
            bf16x8 pf = *(const bf16x8*)(PlB + SWZ(lr, kc * 64 + lg * 16));
#pragma unroll
            for (int nd = 0; nd < 4; ++nd) {
                bf16x8 vf = *(const bf16x8*)(VtB + SWZ(nd * 16 + lr, kc * 64 + lg * 16));
                acc_o[nd] = __builtin_amdgcn_mfma_f32_16x16x32_bf16(vf, pf, acc_o[nd], 0, 0, 0);
            }
        }
    }

    // epilogue: O^T lane holds d=nd*16+lg*4+r for q=lr; write dwordx2 per nd
    float inv = 1.f / l_s;
    u16* orow = &attn_out[(size_t)(b * SEQ + qrow) * DM + h * HD];
#pragma unroll
    for (int nd = 0; nd < 4; ++nd) {
        uint2 u;
        u.x = cvt_pk_bf16(acc_o[nd][0] * inv, acc_o[nd][1] * inv);
        u.y = cvt_pk_bf16(acc_o[nd][2] * inv, acc_o[nd][3] * inv);
        *(uint2*)&orow[nd * 16 + lg * 4] = u;
    }
}

extern "C" void kernel_launch(void* const* d_in, const int* in_sizes, int n_in,
                              void* d_out, int out_size, void* d_ws, size_t ws_size,
                              hipStream_t stream) {
    const float* q_w    = (const float*)d_in[0];
    const float* q_b    = (const float*)d_in[1];
    const float* k_w    = (const float*)d_in[2];
    const float* k_b    = (const float*)d_in[3];
    const float* v_w    = (const float*)d_in[4];
    const float* v_b    = (const float*)d_in[5];
    const float* o_w    = (const float*)d_in[6];
    const float* o_b    = (const float*)d_in[7];
    const float* emb1_w = (const float*)d_in[8];
    const float* emb1_b = (const float*)d_in[9];
    const float* emb2_w = (const float*)d_in[10];
    const float* emb2_b = (const float*)d_in[11];
    const float* log_w  = (const float*)d_in[12];
    const float* log_b  = (const float*)d_in[13];
    const float* prime_w= (const float*)d_in[14];
    const float* prime_b= (const float*)d_in[15];
    const float* div_w  = (const float*)d_in[16];
    const float* div_b  = (const float*)d_in[17];
    const float* bit_w  = (const float*)d_in[18];
    const float* bit_b  = (const float*)d_in[19];
    const float* fus_w  = (const float*)d_in[20];
    const float* fus_b  = (const float*)d_in[21];
    const float* gcd_weight = (const float*)d_in[23];
    const int*   enc    = (const int*)d_in[24];

    char* ws = (char*)d_ws;
    size_t off = 0;
    auto alloc = [&](size_t bytes) {
        char* p = ws + off;
        off += (bytes + 255) & ~size_t(255);
        return p;
    };
    u16*   WcT    = (u16*)alloc((size_t)DM * KF * 2);
    u16*   WqkvT  = (u16*)alloc((size_t)3072 * DM * 2);
    u16*   WoT    = (u16*)alloc((size_t)DM * DM * 2);
    float* cvec   = (float*)alloc(DM * 4);
    float* qkvb   = (float*)alloc(3072 * 4);
    u16*   F      = (u16*)alloc((size_t)NB * SEQ * KF * 2);
    u16*   hidden = (u16*)alloc((size_t)NB * SEQ * DM * 2);
    u16*   qkv    = (u16*)alloc((size_t)NB * SEQ * LDQKV * 2);
    u16*   vT     = (u16*)alloc((size_t)NB * NH * HD * SEQ * 2);
    float* biasMf = (float*)alloc((size_t)NB * SEQ * SEQ * 4);
    u16*   attn_o = (u16*)alloc((size_t)NB * SEQ * DM * 2);
    (void)ws_size; (void)n_in; (void)in_sizes; (void)out_size;

    const float C1 = 0.125f * LOG2E;
    // weight prep (q_w pre-scaled so scores come out in log2 domain)
    transw_kernel<<<dim3(32, 16), dim3(32, 8), 0, stream>>>(emb2_w, WcT, DM, KF, 1.0f);
    transw_kernel<<<dim3(32, 32), dim3(32, 8), 0, stream>>>(q_w, WqkvT, DM, DM, C1);
    transw_kernel<<<dim3(32, 32), dim3(32, 8), 0, stream>>>(k_w, WqkvT + (size_t)1024 * DM, DM, DM, 1.0f);
    transw_kernel<<<dim3(32, 32), dim3(32, 8), 0, stream>>>(v_w, WqkvT + (size_t)2048 * DM, DM, DM, 1.0f);
    transw_kernel<<<dim3(32, 32), dim3(32, 8), 0, stream>>>(o_w, WoT, DM, DM, 1.0f);
    fold_kernel<<<dim3(4, 64), 256, 0, stream>>>(log_w, prime_w, div_w, bit_w, fus_w, WcT);
    cvec_kernel<<<4, 256, 0, stream>>>(emb2_b, fus_b, log_b, prime_b, div_b, bit_b, fus_w, cvec);
    qkvb_kernel<<<12, 256, 0, stream>>>(q_b, k_b, v_b, qkvb);

    // features + hidden (TN=64 -> 512 blocks, 2/CU)
    feat_kernel<<<NB * SEQ, 256, 0, stream>>>(enc, emb1_w, emb1_b, F);
    gemm_kernel<1, 64><<<dim3(DM / 64, NB * SEQ / 128), 256, 0, stream>>>(F, WcT, cvec, hidden,
                                                                          NB * SEQ, DM, KF);
    // qkv (TN=128 -> 768 blocks, 3/CU)
    gemm_kernel<1, 128><<<dim3(3072 / 128, NB * SEQ / 128), 256, 0, stream>>>(hidden, WqkvT, qkvb, qkv,
                                                                              NB * SEQ, 3072, DM);
    vtrans_kernel<<<dim3(SEQ / 64, NH, NB), 256, 0, stream>>>(qkv, vT);
    biasm_kernel<<<dim3(SEQ / 256, SEQ, NB), 256, 0, stream>>>(enc, gcd_weight, biasMf);
    attn_kernel<<<dim3(SEQ / 64, NH, NB), 256, 0, stream>>>(qkv, vT, biasMf, attn_o);
    // output projection (fp32 out, TN=64)
    gemm_kernel<0, 64><<<dim3(DM / 64, NB * SEQ / 128), 256, 0, stream>>>(attn_o, WoT, o_b, d_out,
                                                                          NB * SEQ, DM, DM);
}